// Round 10
// baseline (265.754 us; speedup 1.0000x reference)
//
#include <hip/hip_runtime.h>
#include <cstdint>
#include <cstddef>

// Problem constants (B=4, T=2048, C=1024, H=16, D=64). I/O dtype: fp32.
#define Bsz   4
#define Tsz   2048
#define Csz   1024
#define Hn    16
#define Dh    64
#define Mrows 8192        // B*T
#define KD    1024        // K dim of both GEMMs (= C)

#define NEG_BIG (-1.0e30f)   // finite mask sentinel: exp2(NEG_BIG) flushes to 0
#define SCL2  0.18033688011112042f  // (1/sqrt(64)) * log2(e): folded into Q at
// the QKV epilogue. p = exp2(s) directly; uniform 2^bias cancels in sum(pv)/sum(p).

typedef unsigned short u16;
typedef __bf16  bf16x8 __attribute__((ext_vector_type(8)));
typedef __bf16  bf16x2 __attribute__((ext_vector_type(2)));
typedef float   f32x4  __attribute__((ext_vector_type(4)));
typedef unsigned int u32x4 __attribute__((ext_vector_type(4)));

// Raw barrier + compiler memory fences on both sides (no implicit vmcnt(0)
// drain -- that drain is the structural stall of __syncthreads pipelines).
#define BARRIER() do { asm volatile("" ::: "memory");                          \
                       __builtin_amdgcn_s_barrier();                           \
                       asm volatile("" ::: "memory"); } while (0)

// Literal-immediate vmcnt dispatcher (asm needs compile-time immediates).
template<int N> __device__ __forceinline__ void vmwait() {
  if constexpr (N >= 8)      asm volatile("s_waitcnt vmcnt(8)"  ::: "memory");
  else if constexpr (N == 4) asm volatile("s_waitcnt vmcnt(4)"  ::: "memory");
  else                       asm volatile("s_waitcnt vmcnt(0)"  ::: "memory");
}

__device__ __forceinline__ u16 f2bf(float f) {
  union { float f; unsigned int i; } v; v.f = f;
  unsigned int u = v.i;
  return (u16)((u + 0x7fffu + ((u >> 16) & 1u)) >> 16);   // RNE
}
// Pack two f32 -> two bf16 in one uint (low = a, high = b), RNE.
__device__ __forceinline__ unsigned int pack2bf(float a, float b) {
#if __has_builtin(__builtin_amdgcn_cvt_pk_bf16_f32)
  union { bf16x2 h; unsigned int u; } cv;
  cv.h = __builtin_amdgcn_cvt_pk_bf16_f32(a, b);
  return cv.u;
#else
  return (unsigned int)f2bf(a) | ((unsigned int)f2bf(b) << 16);
#endif
}
// Pack two f32 -> two bf16 by TRUNCATION via one v_perm_b32 (positive P only).
__device__ __forceinline__ unsigned int pack2bf_trunc(float lo, float hi) {
  return __builtin_amdgcn_perm(__builtin_bit_cast(unsigned int, hi),
                               __builtin_bit_cast(unsigned int, lo),
                               0x07060302u);
}
__device__ __forceinline__ float fast_exp2(float x) {
#if __has_builtin(__builtin_amdgcn_exp2f)
  return __builtin_amdgcn_exp2f(x);
#else
  return exp2f(x);
#endif
}

// ---------------------------------------------------------------------------
// Fused preprocessing (ONE launch): region 0 converts x to bf16; regions 1/2
// transpose+convert W_attn / W_proj.
// ---------------------------------------------------------------------------
#define CVT_BLKS  (Mrows * Csz / 4 / 256)   // 8192
#define TRA_BLKS  (48 * 16)                 // W_attn: [1024][3072] -> [3072][1024]
#define TRP_BLKS  (16 * 16)                 // W_proj: [1024][1024] -> [1024][1024]

__global__ __launch_bounds__(256)
void prep(const float* __restrict__ x, u16* __restrict__ xbf,
          const float* __restrict__ Wa, u16* __restrict__ WTa,
          const float* __restrict__ Wp, u16* __restrict__ WTp) {
  __shared__ u16 tile[64][65];
  int bid = blockIdx.x;
  const int tid = threadIdx.x;
  if (bid < CVT_BLKS) {
    const int i = bid * 256 + tid;
    const float4 v = ((const float4*)x)[i];
    uint2 o;
    o.x = pack2bf(v.x, v.y);
    o.y = pack2bf(v.z, v.w);
    ((uint2*)xbf)[i] = o;
    return;
  }
  bid -= CVT_BLKS;
  const float* in; u16* out; int cols, bx, by;
  if (bid < TRA_BLKS) {
    in = Wa; out = WTa; cols = 3 * Csz; bx = bid % 48; by = bid / 48;
  } else {
    bid -= TRA_BLKS;
    in = Wp; out = WTp; cols = Csz; bx = bid & 15; by = bid >> 4;
  }
  const int tc = bx * 64, tr = by * 64;
  const int xx = tid & 63, y0 = tid >> 6;
#pragma unroll
  for (int yy = 0; yy < 64; yy += 4) {
    int r = yy + y0;
    tile[r][xx] = f2bf(in[(size_t)(tr + r) * cols + tc + xx]);
  }
  __syncthreads();
#pragma unroll
  for (int yy = 0; yy < 64; yy += 4) {
    int r = yy + y0;
    out[(size_t)(tc + r) * Csz + tr + xx] = tile[xx][r];
  }
}

// ---------------------------------------------------------------------------
// GEMM C[M,N] = A[M,K] * BT[N,K]^T + bias[N], bf16 in, fp32 acc.
// V8 (round-8, best measured: gemm<0> 74.1 us): 128x128, BK=32, 4 waves 2x2,
// 3-STAGE LDS rotation with ONE barrier per K-step, counted vmcnt(4),
// 4-slot XOR swizzle (pre-swizzled DMA source, 0 conflicts), quadrant-rotated
// reads, setprio, bijective XCD swizzle. 48 KiB LDS -> 3 blocks/CU.
// MODE 0: QKV epilogue -> q/k scatter [bh][t][d]; Q PRE-SCALED by SCL2;
//         V scatter TRANSPOSED [bh][d][t] (packed 8B stores).
// MODE 1: plain epilogue -> fp32 fout[row*N + col].
// ---------------------------------------------------------------------------
template<int MODE>
__global__ __launch_bounds__(256, 3)
void gemm_bt(const u16* __restrict__ A, const u16* __restrict__ BT,
             const float* __restrict__ bias, u16* __restrict__ o0,
             u16* __restrict__ o1, u16* __restrict__ o2,
             float* __restrict__ fout, int N) {
  __shared__ u16 lsA[3][128 * 32];   // [stage][row][32], slot-swizzled content
  __shared__ u16 lsB[3][128 * 32];
  const int tid  = threadIdx.x;
  const int lane = tid & 63;
  const int wid  = tid >> 6;               // 0..3
  const int wm   = wid & 1, wn = wid >> 1; // wave tile 64x64
  const int quad = lane >> 4, l15 = lane & 15;
  const int rswz = (l15 >> 1) & 3;         // read-side XOR (16B-slot units)

  // Bijective XCD-aware swizzle (grid sizes 1536 / 512, both % 8 == 0).
  int bx, by;
  {
    const int nwg  = gridDim.x * gridDim.y;
    const int orig = (int)blockIdx.y * gridDim.x + (int)blockIdx.x;
    const int cpx  = nwg >> 3;
    const int swz  = (orig & 7) * cpx + (orig >> 3);
    bx = swz % gridDim.x; by = swz / gridDim.x;
  }
  const int m0 = by * 128, n0 = bx * 128;

  f32x4 acc[4][4];
#pragma unroll
  for (int i = 0; i < 4; ++i)
#pragma unroll
    for (int j = 0; j < 4; ++j) acc[i][j] = (f32x4){0.f, 0.f, 0.f, 0.f};

  // Staging: per K-step, wave w DMAs A rows [w*32,w*32+32) and B rows same:
  // 2 instrs each (1 instr = 64 lanes x 16B = 16 rows of 64B). Lane l covers
  // row +(l>>2), slot l&3, with PRE-SWIZZLED source chunk (l&3)^((l>>3)&3)
  // so that LDS[r][s] = G[r][s ^ ((r>>1)&3)] with a LINEAR DMA dest.
  const int srow   = lane >> 2;
  const int schunk = (lane & 3) ^ ((lane >> 3) & 3);
  const u16* gA = A  + (size_t)(m0 + wid * 32 + srow) * KD + schunk * 8;
  const u16* gB = BT + (size_t)(n0 + wid * 32 + srow) * KD + schunk * 8;

  auto gstage = [&](int t, int bb) {
#if __has_builtin(__builtin_amdgcn_global_load_lds)
#pragma unroll
    for (int i = 0; i < 2; ++i)
      __builtin_amdgcn_global_load_lds(
          (const __attribute__((address_space(1))) void*)(gA + (size_t)i * 16 * KD + t * 32),
          (__attribute__((address_space(3))) void*)(&lsA[bb][(wid * 32 + i * 16) * 32]),
          16, 0, 0);
#pragma unroll
    for (int i = 0; i < 2; ++i)
      __builtin_amdgcn_global_load_lds(
          (const __attribute__((address_space(1))) void*)(gB + (size_t)i * 16 * KD + t * 32),
          (__attribute__((address_space(3))) void*)(&lsB[bb][(wid * 32 + i * 16) * 32]),
          16, 0, 0);
#else
#pragma unroll
    for (int cc = 0; cc < 2; ++cc) {
      const int c = tid + cc * 256;
      const int rr = c >> 2, off = c & 3;
      const int dc = (off ^ ((rr >> 1) & 3)) << 3;
      *(uint4*)&lsA[bb][rr * 32 + dc] =
          *(const uint4*)&A[(size_t)(m0 + rr) * KD + t * 32 + off * 8];
    }
#pragma unroll
    for (int cc = 0; cc < 2; ++cc) {
      const int c = tid + cc * 256;
      const int rr = c >> 2, off = c & 3;
      const int dc = (off ^ ((rr >> 1) & 3)) << 3;
      *(uint4*)&lsB[bb][rr * 32 + dc] =
          *(const uint4*)&BT[(size_t)(n0 + rr) * KD + t * 32 + off * 8];
    }
#endif
  };

  // Fragment read helpers. Row within tile: base + m*16 + l15; swizzle term
  // depends only on l15 (bases contribute multiples of 8 to row>>1).
#define READ_B(n_) (*(const bf16x8*)                                           \
    &lsB[cur][(wn * 64 + (n_) * 16 + l15) * 32 + ((quad ^ rswz) << 3)])
#define READ_A(m_) (*(const bf16x8*)                                           \
    &lsA[cur][(wm * 64 + (m_) * 16 + l15) * 32 + ((quad ^ rswz) << 3)])
#define MFMA_ROW(m_, src)                                                      \
  __builtin_amdgcn_s_setprio(1);                                               \
  _Pragma("unroll")                                                            \
  for (int n = 0; n < 4; ++n)                                                  \
    acc[m_][n] = __builtin_amdgcn_mfma_f32_16x16x32_bf16(                      \
        src, bfv[n], acc[m_][n], 0, 0, 0);                                     \
  __builtin_amdgcn_s_setprio(0);

  // 3-stage prologue: stages 0 and 1 in flight (8 DMA outstanding).
  gstage(0, 0); gstage(1, 1);
  const int KT = KD / 32;   // 32
  int cur = 0;
  for (int t = 0; t < KT; ++t) {
    if (t < KT - 1) vmwait<4>();   // own ledger: 8 out -> stage t landed,
    else            vmwait<0>();   // stage t+1's 4 stay in flight
    BARRIER();   // buf[cur] globally complete; reads of buf[(t-1)%3] all done

    if (t + 2 < KT) {
      int nb2 = cur + 2; if (nb2 >= 3) nb2 -= 3;   // == (t-1)%3: freed above
      gstage(t + 2, nb2);
    }

    bf16x8 bfv[4];
#pragma unroll
    for (int n = 0; n < 4; ++n) bfv[n] = READ_B(n);
    bf16x8 afA = READ_A(0);
    bf16x8 afB = READ_A(1);
    MFMA_ROW(0, afA);
    afA = READ_A(2);
    MFMA_ROW(1, afB);
    afB = READ_A(3);
    MFMA_ROW(2, afA);
    MFMA_ROW(3, afB);

    cur = (cur == 2) ? 0 : cur + 1;   // single barrier per step: no tail sync
  }
#undef READ_B
#undef READ_A
#undef MFMA_ROW

  // Epilogue. C/D layout: col = lane&15, row = quad*4 + r (verified m89/m91).
#pragma unroll
  for (int i = 0; i < 4; ++i) {
#pragma unroll
    for (int j = 0; j < 4; ++j) {
      const int colb = n0 + wn * 64 + j * 16 + l15;
      const float bv = bias[colb];
      float vals[4];
#pragma unroll
      for (int r = 0; r < 4; ++r) vals[r] = acc[i][j][r] + bv;
      const int row0 = m0 + wm * 64 + i * 16 + quad * 4;
      if (MODE == 0) {
        const int b = row0 >> 11, t0 = row0 & (Tsz - 1);
        const int region = colb >> 10;        // 0:q 1:k 2:v (fragment-uniform)
        const int nc = colb & (Csz - 1);
        const int h = nc >> 6, d = nc & 63;
        if (region == 2) {
          // V transposed: [bh][d][t]; 4 consecutive t -> one 8B store.
          uint2 st;
          st.x = pack2bf(vals[0], vals[1]);
          st.y = pack2bf(vals[2], vals[3]);
          *(uint2*)&o2[((size_t)((b << 4) + h) * Dh + d) * Tsz + t0] = st;
        } else {
          u16* dst = (region == 0) ? o0 : o1;
          const float qs = (region == 0) ? SCL2 : 1.0f;  // fold softmax scale
#pragma unroll
          for (int r = 0; r < 4; ++r)
            dst[(size_t)(((b << 4) + h) * Tsz + t0 + r) * Dh + d] =
                f2bf(vals[r] * qs);
        }
      } else {
#pragma unroll
        for (int r = 0; r < 4; ++r)
          fout[(size_t)(row0 + r) * N + colb] = vals[r];
      }
    }
  }
}

// ---------------------------------------------------------------------------
// Fused causal flash attention, V10: round-5 compute body + the round-8
// barrier topology: 3-STAGE K/V rotation, ONE barrier per KV-tile (was 2).
//   iter j: vmwait(4) [own stage-j slice landed; in-order vmcnt retirement
//   means leftover epilogue stores only make this conservative] -> BARRIER
//   [buf j%3 globally complete AND all reads of buf (j-1)%3 done] -> issue
//   STAGE(j+2) into buf (j+2)%3 == (j-1)%3 [race-free] -> compute.
// Phase-start BARRIER protects buffers from the previous phase's last
// readers (no trailing barrier inside the loop). Prologue stages tiles 0,1
// unconditionally (tile 1 always within the bh's K/V allocation; unused
// when jq == 0 -- vmwait<0> on the last iter drains it).
// LDS 48 KiB (3x8K K + 3x8K V) -> 3 blocks/CU.
// grid (bh=64, y=16), 256 threads; block handles jq=31-y then jq=y.
// ---------------------------------------------------------------------------
__global__ __launch_bounds__(256)
void attn_fused(const u16* __restrict__ qb, const u16* __restrict__ kbuf,
                const u16* __restrict__ vT, u16* __restrict__ outp) {
  __shared__ u16 Kl[3][64 * 64];   // [stage][key][d],  chunk-swizzled content
  __shared__ u16 Vt[3][64 * 64];   // [stage][d][key],  chunk-swizzled content
  const int tid = threadIdx.x, lane = tid & 63, w = tid >> 6;
  const int quad = lane >> 4, l15 = lane & 15;
  const int cswz = (l15 & 7) << 3;        // read-side XOR swizzle (u16 units)
  const int bh = blockIdx.x;
  const int b = bh >> 4, h = bh & 15;
  const u16* Q   = qb   + (size_t)bh * Tsz * Dh;
  const u16* Kg  = kbuf + (size_t)bh * Tsz * Dh;
  const u16* VTg = vT   + (size_t)bh * Dh * Tsz;

  const int srow   = lane >> 3;
  const int schunk = ((lane & 7) ^ srow) << 3;       // u16 offset in row
  const u16* gK0 = Kg  + (size_t)(w * 16 + srow) * Dh  + schunk;
  const u16* gV0 = VTg + (size_t)(w * 16 + srow) * Tsz + schunk;

#if __has_builtin(__builtin_amdgcn_global_load_lds)
#define STAGE(jj, bb) do {                                                     \
    const size_t kb_ = (size_t)(jj) * 64;                                      \
    _Pragma("unroll")                                                          \
    for (int i_ = 0; i_ < 2; ++i_) {                                           \
      __builtin_amdgcn_global_load_lds(                                        \
        (const __attribute__((address_space(1))) void*)(gK0 + (kb_ + (size_t)i_ * 8) * Dh), \
        (__attribute__((address_space(3))) void*)(&Kl[bb][(w * 16 + i_ * 8) * 64]), 16, 0, 0); \
      __builtin_amdgcn_global_load_lds(                                        \
        (const __attribute__((address_space(1))) void*)(gV0 + (size_t)(i_ * 8) * Tsz + kb_), \
        (__attribute__((address_space(3))) void*)(&Vt[bb][(w * 16 + i_ * 8) * 64]), 16, 0, 0); \
    }                                                                          \
  } while (0)
#else
#define STAGE(jj, bb) do {                                                     \
    const int kb_ = (jj) * 64;                                                 \
    _Pragma("unroll")                                                          \
    for (int cc_ = 0; cc_ < 2; ++cc_) {                                        \
      const int c_ = tid + cc_ * 256;                                          \
      const int rr_ = c_ >> 3, off_ = c_ & 7;                                  \
      const int dc_ = (off_ ^ (rr_ & 7)) << 3;                                 \
      *(uint4*)&Kl[bb][rr_ * 64 + dc_] =                                       \
          *(const uint4*)&Kg[(size_t)(kb_ + rr_) * Dh + off_ * 8];             \
      *(uint4*)&Vt[bb][rr_ * 64 + dc_] =                                       \
          *(const uint4*)&VTg[(size_t)rr_ * Tsz + kb_ + off_ * 8];             \
    }                                                                          \
  } while (0)
#endif

  for (int ph = 0; ph < 2; ++ph) {
    const int jq = ph ? (int)blockIdx.y : 31 - (int)blockIdx.y;

    // Q fragment (B-operand of S^T): lane holds Q[q=l15][d=quad*8+j].
    const int qrow = jq * 64 + w * 16 + l15;   // this lane's q (global row)
    const bf16x8 bq0 = *(const bf16x8*)&Q[(size_t)qrow * Dh + quad * 8];
    const bf16x8 bq1 = *(const bf16x8*)&Q[(size_t)qrow * Dh + 32 + quad * 8];

    f32x4 O[4];    // O^T: col q = l15, row d = nb*16 + quad*4 + r
#pragma unroll
    for (int nb = 0; nb < 4; ++nb) O[nb] = (f32x4){0.f, 0.f, 0.f, 0.f};
    float l_i = 0.f;               // per-lane partial sum (16 keys/lane/tile)

    BARRIER();   // previous phase's last readers are done before re-staging
    STAGE(0, 0);
    STAGE(1, 1);   // 8 DMA outstanding (tile 1 unused if jq==0: drained below)

    int cur = 0;
    for (int j = 0; j <= jq; ++j) {
      if (j < jq) vmwait<4>();   // own ledger: stage j landed; j+1 in flight
      else        vmwait<0>();
      BARRIER();   // buf[cur] globally complete; reads of buf[(j-1)%3] done

      if (j + 2 <= jq) {
        int nb2 = cur + 2; if (nb2 >= 3) nb2 -= 3;   // == (j-1)%3: freed above
        STAGE(j + 2, nb2);
      }

      const int kb = j * 64;
      const bool diag = (j == jq);
      const int tmax = diag ? (w + 1) : 4;   // 16-key sub-tiles with any work
      const u16* KT = Kl[cur];
      const u16* VL = Vt[cur];

      // S^T: A = K fragment (m=key=16t+l15, k=d=quad*8+jj), B = Q fragment.
      f32x4 S[4];
#pragma unroll
      for (int t = 0; t < 4; ++t) S[t] = (f32x4){0.f, 0.f, 0.f, 0.f};
      __builtin_amdgcn_s_setprio(1);
#pragma unroll
      for (int t = 0; t < 4; ++t) {
        if (t < tmax) {
          bf16x8 ak = *(const bf16x8*)&KT[(t * 16 + l15) * 64 + ((quad * 8) ^ cswz)];
          S[t] = __builtin_amdgcn_mfma_f32_16x16x32_bf16(ak, bq0, S[t], 0, 0, 0);
          ak = *(const bf16x8*)&KT[(t * 16 + l15) * 64 + ((quad * 8 + 32) ^ cswz)];
          S[t] = __builtin_amdgcn_mfma_f32_16x16x32_bf16(ak, bq1, S[t], 0, 0, 0);
        }
      }
      __builtin_amdgcn_s_setprio(0);

      // p = exp2(s) directly (scale pre-folded into Q); masked -> 0.
      float p[4][4];
      if (diag) {
#pragma unroll
        for (int t = 0; t < 4; ++t) {
          const int key0 = kb + t * 16 + quad * 4;
#pragma unroll
          for (int r = 0; r < 4; ++r) {
            const float sv =
                (t < tmax && key0 + r <= qrow) ? S[t][r] : NEG_BIG;
            p[t][r] = fast_exp2(sv);
            l_i += p[t][r];
          }
        }
      } else {
#pragma unroll
        for (int t = 0; t < 4; ++t)
#pragma unroll
          for (int r = 0; r < 4; ++r) {
            p[t][r] = fast_exp2(S[t][r]);
            l_i += p[t][r];
          }
      }

      // PV chunk 0 (keys 0..31 = tiles 0,1): B-frag key pi(quad*8+jj).
      u32x4 pu;
      pu[0] = pack2bf_trunc(p[0][0], p[0][1]);
      pu[1] = pack2bf_trunc(p[0][2], p[0][3]);
      pu[2] = pack2bf_trunc(p[1][0], p[1][1]);
      pu[3] = pack2bf_trunc(p[1][2], p[1][3]);
      bf16x8 pb = __builtin_bit_cast(bf16x8, pu);
      __builtin_amdgcn_s_setprio(1);
#pragma unroll
      for (int nb = 0; nb < 4; ++nb) {
        const uint2 a0 = *(const uint2*)&VL[(nb * 16 + l15) * 64 + ((quad * 4) ^ cswz)];
        const uint2 a1 = *(const uint2*)&VL[(nb * 16 + l15) * 64 + ((quad * 4 + 16) ^ cswz)];
        const u32x4 au = {a0.x, a0.y, a1.x, a1.y};
        O[nb] = __builtin_amdgcn_mfma_f32_16x16x32_bf16(
            __builtin_bit_cast(bf16x8, au), pb, O[nb], 0, 0, 0);
      }
      __builtin_amdgcn_s_setprio(0);
      if (tmax > 2) {   // PV chunk 1 (keys 32..63 = tiles 2,3)
        pu[0] = pack2bf_trunc(p[2][0], p[2][1]);
        pu[1] = pack2bf_trunc(p[2][2], p[2][3]);
        pu[2] = pack2bf_trunc(p[3][0], p[3][1]);
        pu[3] = pack2bf_trunc(p[3][2], p[3][3]);
        pb = __builtin_bit_cast(bf16x8, pu);
        __builtin_amdgcn_s_setprio(1);
#pragma unroll
        for (int nb = 0; nb < 4; ++nb) {
          const uint2 a0 = *(const uint2*)&VL[(nb * 16 + l15) * 64 + ((quad * 4 + 32) ^ cswz)];
          const uint2 a1 = *(const uint2*)&VL[(nb * 16 + l15) * 64 + ((quad * 4 + 48) ^ cswz)];
          const u32x4 au = {a0.x, a0.y, a1.x, a1.y};
          O[nb] = __builtin_amdgcn_mfma_f32_16x16x32_bf16(
              __builtin_bit_cast(bf16x8, au), pb, O[nb], 0, 0, 0);
        }
        __builtin_amdgcn_s_setprio(0);
      }
      cur = (cur == 2) ? 0 : cur + 1;   // single barrier per tile
    }

    // One cross-lane l reduction for the whole phase, then write out.
    float lt = l_i + __shfl_xor(l_i, 16, 64);
    lt += __shfl_xor(lt, 32, 64);
    const float inv = 1.0f / lt;
#pragma unroll
    for (int nb = 0; nb < 4; ++nb) {
      uint2 st;
      st.x = pack2bf(O[nb][0] * inv, O[nb][1] * inv);
      st.y = pack2bf(O[nb][2] * inv, O[nb][3] * inv);
      *(uint2*)&outp[(size_t)(b * Tsz + qrow) * Csz + h * Dh + nb * 16 + quad * 4] = st;
    }
  }
#undef STAGE
}

// ---------------------------------------------------------------------------
extern "C" void kernel_launch(void* const* d_in, const int* in_sizes, int n_in,
                              void* d_out, int out_size, void* d_ws, size_t ws_size,
                              hipStream_t stream) {
  const float* x      = (const float*)d_in[0];   // [B,T,C] fp32
  const float* W_attn = (const float*)d_in[1];   // [C,3C]  fp32
  const float* b_attn = (const float*)d_in[2];   // [3C]    fp32
  const float* W_proj = (const float*)d_in[3];   // [C,C]   fp32
  const float* b_proj = (const float*)d_in[4];   // [C]     fp32
  float* out = (float*)d_out;                    // [B,T,C] fp32

  u16* ws   = (u16*)d_ws;
  u16* xbf  = ws;                                // [B,T,C] bf16
  u16* qbuf = xbf  + (size_t)Mrows * Csz;        // [bh][t][d] (pre-scaled)
  u16* kbuf = qbuf + (size_t)Mrows * Csz;        // [bh][t][d]
  u16* vbuf = kbuf + (size_t)Mrows * Csz;        // [bh][d][t]  (transposed!)
  u16* aout = vbuf + (size_t)Mrows * Csz;        // [B,T,C] bf16
  u16* WTa  = aout + (size_t)Mrows * Csz;        // [3C][C] bf16
  u16* WTp  = WTa  + (size_t)Csz * 3 * Csz;      // [C][C]  bf16

  prep<<<CVT_BLKS + TRA_BLKS + TRP_BLKS, 256, 0, stream>>>(
      x, xbf, W_attn, WTa, W_proj, WTp);
  // 128x128 tile, 256 thr: grid 24x64 = 1536 blocks, 3 blocks/CU.
  gemm_bt<0><<<dim3(3 * Csz / 128, Mrows / 128), dim3(256), 0, stream>>>(
      xbf, WTa, b_attn, qbuf, kbuf, vbuf, nullptr, 3 * Csz);
  attn_fused<<<dim3(Bsz * Hn, Tsz / 128), 256, 0, stream>>>(
      qbuf, kbuf, vbuf, aout);
  // 128x128 tile, 256 thr: grid 8x64 = 512 blocks.
  gemm_bt<1><<<dim3(Csz / 128, Mrows / 128), dim3(256), 0, stream>>>(
      aout, WTp, b_proj, nullptr, nullptr, nullptr, out, Csz);
}

// Round 11
// 255.338 us; speedup vs baseline: 1.0408x; 1.0408x over previous
//
#include <hip/hip_runtime.h>
#include <cstdint>
#include <cstddef>

// Problem constants (B=4, T=2048, C=1024, H=16, D=64). I/O dtype: fp32.
#define Bsz   4
#define Tsz   2048
#define Csz   1024
#define Hn    16
#define Dh    64
#define Mrows 8192        // B*T
#define KD    1024        // K dim of both GEMMs (= C)

#define NEG_BIG (-1.0e30f)   // finite mask sentinel: exp2(NEG_BIG) flushes to 0
#define SCL2  0.18033688011112042f  // (1/sqrt(64)) * log2(e): folded into Q at
// the QKV epilogue. p = exp2(s) directly; uniform 2^bias cancels in sum(pv)/sum(p).

typedef unsigned short u16;
typedef __bf16  bf16x8 __attribute__((ext_vector_type(8)));
typedef __bf16  bf16x2 __attribute__((ext_vector_type(2)));
typedef float   f32x4  __attribute__((ext_vector_type(4)));
typedef unsigned int u32x4 __attribute__((ext_vector_type(4)));

// Raw barrier + compiler memory fences on both sides (no implicit vmcnt(0)
// drain -- that drain is the structural stall of __syncthreads pipelines).
#define BARRIER() do { asm volatile("" ::: "memory");                          \
                       __builtin_amdgcn_s_barrier();                           \
                       asm volatile("" ::: "memory"); } while (0)

// Literal-immediate vmcnt dispatcher (asm needs compile-time immediates).
template<int N> __device__ __forceinline__ void vmwait() {
  if constexpr (N >= 8)      asm volatile("s_waitcnt vmcnt(8)"  ::: "memory");
  else if constexpr (N == 4) asm volatile("s_waitcnt vmcnt(4)"  ::: "memory");
  else                       asm volatile("s_waitcnt vmcnt(0)"  ::: "memory");
}

__device__ __forceinline__ u16 f2bf(float f) {
  union { float f; unsigned int i; } v; v.f = f;
  unsigned int u = v.i;
  return (u16)((u + 0x7fffu + ((u >> 16) & 1u)) >> 16);   // RNE
}
// Pack two f32 -> two bf16 in one uint (low = a, high = b), RNE.
__device__ __forceinline__ unsigned int pack2bf(float a, float b) {
#if __has_builtin(__builtin_amdgcn_cvt_pk_bf16_f32)
  union { bf16x2 h; unsigned int u; } cv;
  cv.h = __builtin_amdgcn_cvt_pk_bf16_f32(a, b);
  return cv.u;
#else
  return (unsigned int)f2bf(a) | ((unsigned int)f2bf(b) << 16);
#endif
}
// Pack two f32 -> two bf16 by TRUNCATION via one v_perm_b32 (positive P only).
__device__ __forceinline__ unsigned int pack2bf_trunc(float lo, float hi) {
  return __builtin_amdgcn_perm(__builtin_bit_cast(unsigned int, hi),
                               __builtin_bit_cast(unsigned int, lo),
                               0x07060302u);
}
__device__ __forceinline__ float fast_exp2(float x) {
#if __has_builtin(__builtin_amdgcn_exp2f)
  return __builtin_amdgcn_exp2f(x);
#else
  return exp2f(x);
#endif
}

// ---------------------------------------------------------------------------
// Fused preprocessing (ONE launch): region 0 converts x to bf16; regions 1/2
// transpose+convert W_attn / W_proj.
// ---------------------------------------------------------------------------
#define CVT_BLKS  (Mrows * Csz / 4 / 256)   // 8192
#define TRA_BLKS  (48 * 16)                 // W_attn: [1024][3072] -> [3072][1024]
#define TRP_BLKS  (16 * 16)                 // W_proj: [1024][1024] -> [1024][1024]

__global__ __launch_bounds__(256)
void prep(const float* __restrict__ x, u16* __restrict__ xbf,
          const float* __restrict__ Wa, u16* __restrict__ WTa,
          const float* __restrict__ Wp, u16* __restrict__ WTp) {
  __shared__ u16 tile[64][65];
  int bid = blockIdx.x;
  const int tid = threadIdx.x;
  if (bid < CVT_BLKS) {
    const int i = bid * 256 + tid;
    const float4 v = ((const float4*)x)[i];
    uint2 o;
    o.x = pack2bf(v.x, v.y);
    o.y = pack2bf(v.z, v.w);
    ((uint2*)xbf)[i] = o;
    return;
  }
  bid -= CVT_BLKS;
  const float* in; u16* out; int cols, bx, by;
  if (bid < TRA_BLKS) {
    in = Wa; out = WTa; cols = 3 * Csz; bx = bid % 48; by = bid / 48;
  } else {
    bid -= TRA_BLKS;
    in = Wp; out = WTp; cols = Csz; bx = bid & 15; by = bid >> 4;
  }
  const int tc = bx * 64, tr = by * 64;
  const int xx = tid & 63, y0 = tid >> 6;
#pragma unroll
  for (int yy = 0; yy < 64; yy += 4) {
    int r = yy + y0;
    tile[r][xx] = f2bf(in[(size_t)(tr + r) * cols + tc + xx]);
  }
  __syncthreads();
#pragma unroll
  for (int yy = 0; yy < 64; yy += 4) {
    int r = yy + y0;
    out[(size_t)(tc + r) * Csz + tr + xx] = tile[xx][r];
  }
}

// ---------------------------------------------------------------------------
// GEMM C[M,N] = A[M,K] * BT[N,K]^T + bias[N], bf16 in, fp32 acc.
// V8 (round-8, best measured: gemm<0> 74.1 us): 128x128, BK=32, 4 waves 2x2,
// 3-STAGE LDS rotation with ONE barrier per K-step, counted vmcnt(4),
// 4-slot XOR swizzle (pre-swizzled DMA source, 0 conflicts), quadrant-rotated
// reads, setprio, bijective XCD swizzle. 48 KiB LDS -> 3 blocks/CU
// (grid 1536 = 2 x 768 resident: exactly 2 full rounds, no partial tail).
// MODE 0: QKV epilogue -> q/k scatter [bh][t][d]; Q PRE-SCALED by SCL2;
//         V scatter TRANSPOSED [bh][d][t] (packed 8B stores).
// MODE 1: plain epilogue -> fp32 fout[row*N + col].
// ---------------------------------------------------------------------------
template<int MODE>
__global__ __launch_bounds__(256, 3)
void gemm_bt(const u16* __restrict__ A, const u16* __restrict__ BT,
             const float* __restrict__ bias, u16* __restrict__ o0,
             u16* __restrict__ o1, u16* __restrict__ o2,
             float* __restrict__ fout, int N) {
  __shared__ u16 lsA[3][128 * 32];   // [stage][row][32], slot-swizzled content
  __shared__ u16 lsB[3][128 * 32];
  const int tid  = threadIdx.x;
  const int lane = tid & 63;
  const int wid  = tid >> 6;               // 0..3
  const int wm   = wid & 1, wn = wid >> 1; // wave tile 64x64
  const int quad = lane >> 4, l15 = lane & 15;
  const int rswz = (l15 >> 1) & 3;         // read-side XOR (16B-slot units)

  // Bijective XCD-aware swizzle (grid sizes 1536 / 512, both % 8 == 0).
  int bx, by;
  {
    const int nwg  = gridDim.x * gridDim.y;
    const int orig = (int)blockIdx.y * gridDim.x + (int)blockIdx.x;
    const int cpx  = nwg >> 3;
    const int swz  = (orig & 7) * cpx + (orig >> 3);
    bx = swz % gridDim.x; by = swz / gridDim.x;
  }
  const int m0 = by * 128, n0 = bx * 128;

  f32x4 acc[4][4];
#pragma unroll
  for (int i = 0; i < 4; ++i)
#pragma unroll
    for (int j = 0; j < 4; ++j) acc[i][j] = (f32x4){0.f, 0.f, 0.f, 0.f};

  // Staging: per K-step, wave w DMAs A rows [w*32,w*32+32) and B rows same:
  // 2 instrs each (1 instr = 64 lanes x 16B = 16 rows of 64B). Lane l covers
  // row +(l>>2), slot l&3, with PRE-SWIZZLED source chunk (l&3)^((l>>3)&3)
  // so that LDS[r][s] = G[r][s ^ ((r>>1)&3)] with a LINEAR DMA dest.
  const int srow   = lane >> 2;
  const int schunk = (lane & 3) ^ ((lane >> 3) & 3);
  const u16* gA = A  + (size_t)(m0 + wid * 32 + srow) * KD + schunk * 8;
  const u16* gB = BT + (size_t)(n0 + wid * 32 + srow) * KD + schunk * 8;

  auto gstage = [&](int t, int bb) {
#if __has_builtin(__builtin_amdgcn_global_load_lds)
#pragma unroll
    for (int i = 0; i < 2; ++i)
      __builtin_amdgcn_global_load_lds(
          (const __attribute__((address_space(1))) void*)(gA + (size_t)i * 16 * KD + t * 32),
          (__attribute__((address_space(3))) void*)(&lsA[bb][(wid * 32 + i * 16) * 32]),
          16, 0, 0);
#pragma unroll
    for (int i = 0; i < 2; ++i)
      __builtin_amdgcn_global_load_lds(
          (const __attribute__((address_space(1))) void*)(gB + (size_t)i * 16 * KD + t * 32),
          (__attribute__((address_space(3))) void*)(&lsB[bb][(wid * 32 + i * 16) * 32]),
          16, 0, 0);
#else
#pragma unroll
    for (int cc = 0; cc < 2; ++cc) {
      const int c = tid + cc * 256;
      const int rr = c >> 2, off = c & 3;
      const int dc = (off ^ ((rr >> 1) & 3)) << 3;
      *(uint4*)&lsA[bb][rr * 32 + dc] =
          *(const uint4*)&A[(size_t)(m0 + rr) * KD + t * 32 + off * 8];
    }
#pragma unroll
    for (int cc = 0; cc < 2; ++cc) {
      const int c = tid + cc * 256;
      const int rr = c >> 2, off = c & 3;
      const int dc = (off ^ ((rr >> 1) & 3)) << 3;
      *(uint4*)&lsB[bb][rr * 32 + dc] =
          *(const uint4*)&BT[(size_t)(n0 + rr) * KD + t * 32 + off * 8];
    }
#endif
  };

  // Fragment read helpers. Row within tile: base + m*16 + l15; swizzle term
  // depends only on l15 (bases contribute multiples of 8 to row>>1).
#define READ_B(n_) (*(const bf16x8*)                                           \
    &lsB[cur][(wn * 64 + (n_) * 16 + l15) * 32 + ((quad ^ rswz) << 3)])
#define READ_A(m_) (*(const bf16x8*)                                           \
    &lsA[cur][(wm * 64 + (m_) * 16 + l15) * 32 + ((quad ^ rswz) << 3)])
#define MFMA_ROW(m_, src)                                                      \
  __builtin_amdgcn_s_setprio(1);                                               \
  _Pragma("unroll")                                                            \
  for (int n = 0; n < 4; ++n)                                                  \
    acc[m_][n] = __builtin_amdgcn_mfma_f32_16x16x32_bf16(                      \
        src, bfv[n], acc[m_][n], 0, 0, 0);                                     \
  __builtin_amdgcn_s_setprio(0);

  // 3-stage prologue: stages 0 and 1 in flight (8 DMA outstanding).
  gstage(0, 0); gstage(1, 1);
  const int KT = KD / 32;   // 32
  int cur = 0;
  for (int t = 0; t < KT; ++t) {
    if (t < KT - 1) vmwait<4>();   // own ledger: 8 out -> stage t landed,
    else            vmwait<0>();   // stage t+1's 4 stay in flight
    BARRIER();   // buf[cur] globally complete; reads of buf[(t-1)%3] all done

    if (t + 2 < KT) {
      int nb2 = cur + 2; if (nb2 >= 3) nb2 -= 3;   // == (t-1)%3: freed above
      gstage(t + 2, nb2);
    }

    bf16x8 bfv[4];
#pragma unroll
    for (int n = 0; n < 4; ++n) bfv[n] = READ_B(n);
    bf16x8 afA = READ_A(0);
    bf16x8 afB = READ_A(1);
    MFMA_ROW(0, afA);
    afA = READ_A(2);
    MFMA_ROW(1, afB);
    afB = READ_A(3);
    MFMA_ROW(2, afA);
    MFMA_ROW(3, afB);

    cur = (cur == 2) ? 0 : cur + 1;   // single barrier per step: no tail sync
  }
#undef READ_B
#undef READ_A
#undef MFMA_ROW

  // Epilogue. C/D layout: col = lane&15, row = quad*4 + r (verified m89/m91).
#pragma unroll
  for (int i = 0; i < 4; ++i) {
#pragma unroll
    for (int j = 0; j < 4; ++j) {
      const int colb = n0 + wn * 64 + j * 16 + l15;
      const float bv = bias[colb];
      float vals[4];
#pragma unroll
      for (int r = 0; r < 4; ++r) vals[r] = acc[i][j][r] + bv;
      const int row0 = m0 + wm * 64 + i * 16 + quad * 4;
      if (MODE == 0) {
        const int b = row0 >> 11, t0 = row0 & (Tsz - 1);
        const int region = colb >> 10;        // 0:q 1:k 2:v (fragment-uniform)
        const int nc = colb & (Csz - 1);
        const int h = nc >> 6, d = nc & 63;
        if (region == 2) {
          // V transposed: [bh][d][t]; 4 consecutive t -> one 8B store.
          uint2 st;
          st.x = pack2bf(vals[0], vals[1]);
          st.y = pack2bf(vals[2], vals[3]);
          *(uint2*)&o2[((size_t)((b << 4) + h) * Dh + d) * Tsz + t0] = st;
        } else {
          u16* dst = (region == 0) ? o0 : o1;
          const float qs = (region == 0) ? SCL2 : 1.0f;  // fold softmax scale
#pragma unroll
          for (int r = 0; r < 4; ++r)
            dst[(size_t)(((b << 4) + h) * Tsz + t0 + r) * Dh + d] =
                f2bf(vals[r] * qs);
        }
      } else {
#pragma unroll
        for (int r = 0; r < 4; ++r)
          fout[(size_t)(row0 + r) * N + colb] = vals[r];
      }
    }
  }
}

// ---------------------------------------------------------------------------
// Fused causal flash attention, V11: QBLK=128 per block (2 q-fragments per
// wave sharing ALL K and V LDS reads) + single-barrier 3-stage K/V rotation.
// Per unit work vs the 64-row version: staging volume, barrier count, and
// LDS reads all HALVE; exp/pack VALU unchanged. Grid 64x8 = 512 blocks ->
// all-resident at 3 blocks/CU (48 KiB LDS), zero tail (round-10 lesson).
// Pairing: phase 0 handles Qi = 15-y, phase 1 handles Qi = y: every block
// visits (2(15-y)+2) + (2y+2) = 34 KV-tiles -- uniform.
// Masking (generalizes the verified tmax=w+1 scheme): frag f of wave w has
// q sub-tile index Q16 = 8*Qi + 2w + f; rel_f = Q16 - 4j;
// tmax_f = min(4, rel_f+1); rel_f >= 4 -> plain exp; 0 <= rel_f <= 3 ->
// element-masked exp (key0+r <= qrow_f); tmax_f <= 0 -> frag skipped.
// All flags wave-uniform (depend on w, j only).
// ---------------------------------------------------------------------------
__global__ __launch_bounds__(256)
void attn_fused(const u16* __restrict__ qb, const u16* __restrict__ kbuf,
                const u16* __restrict__ vT, u16* __restrict__ outp) {
  __shared__ u16 Kl[3][64 * 64];   // [stage][key][d],  chunk-swizzled content
  __shared__ u16 Vt[3][64 * 64];   // [stage][d][key],  chunk-swizzled content
  const int tid = threadIdx.x, lane = tid & 63, w = tid >> 6;
  const int quad = lane >> 4, l15 = lane & 15;
  const int cswz = (l15 & 7) << 3;        // read-side XOR swizzle (u16 units)
  const int bh = blockIdx.x;
  const int b = bh >> 4, h = bh & 15;
  const u16* Q   = qb   + (size_t)bh * Tsz * Dh;
  const u16* Kg  = kbuf + (size_t)bh * Tsz * Dh;
  const u16* VTg = vT   + (size_t)bh * Dh * Tsz;

  const int srow   = lane >> 3;
  const int schunk = ((lane & 7) ^ srow) << 3;       // u16 offset in row
  const u16* gK0 = Kg  + (size_t)(w * 16 + srow) * Dh  + schunk;
  const u16* gV0 = VTg + (size_t)(w * 16 + srow) * Tsz + schunk;

#if __has_builtin(__builtin_amdgcn_global_load_lds)
#define STAGE(jj, bb) do {                                                     \
    const size_t kb_ = (size_t)(jj) * 64;                                      \
    _Pragma("unroll")                                                          \
    for (int i_ = 0; i_ < 2; ++i_) {                                           \
      __builtin_amdgcn_global_load_lds(                                        \
        (const __attribute__((address_space(1))) void*)(gK0 + (kb_ + (size_t)i_ * 8) * Dh), \
        (__attribute__((address_space(3))) void*)(&Kl[bb][(w * 16 + i_ * 8) * 64]), 16, 0, 0); \
      __builtin_amdgcn_global_load_lds(                                        \
        (const __attribute__((address_space(1))) void*)(gV0 + (size_t)(i_ * 8) * Tsz + kb_), \
        (__attribute__((address_space(3))) void*)(&Vt[bb][(w * 16 + i_ * 8) * 64]), 16, 0, 0); \
    }                                                                          \
  } while (0)
#else
#define STAGE(jj, bb) do {                                                     \
    const int kb_ = (jj) * 64;                                                 \
    _Pragma("unroll")                                                          \
    for (int cc_ = 0; cc_ < 2; ++cc_) {                                        \
      const int c_ = tid + cc_ * 256;                                          \
      const int rr_ = c_ >> 3, off_ = c_ & 7;                                  \
      const int dc_ = (off_ ^ (rr_ & 7)) << 3;                                 \
      *(uint4*)&Kl[bb][rr_ * 64 + dc_] =                                       \
          *(const uint4*)&Kg[(size_t)(kb_ + rr_) * Dh + off_ * 8];             \
      *(uint4*)&Vt[bb][rr_ * 64 + dc_] =                                       \
          *(const uint4*)&VTg[(size_t)rr_ * Tsz + kb_ + off_ * 8];             \
    }                                                                          \
  } while (0)
#endif

  for (int ph = 0; ph < 2; ++ph) {
    const int Qi   = ph ? (int)blockIdx.y : 15 - (int)blockIdx.y;
    const int qb0  = Qi * 128;
    const int jmax = 2 * Qi + 1;            // KV tiles 0..jmax (>=1 always)
    const int Q16_0 = Qi * 8 + w * 2;       // frag0 q sub-tile; frag1 = +1
    const int qrow0 = qb0 + w * 32 + l15;   // frag0 q row of this lane
    const int qrow1 = qrow0 + 16;           // frag1

    // Q fragments (B-operand of S^T): lane holds Q[q][d=quad*8+j].
    const bf16x8 bq00 = *(const bf16x8*)&Q[(size_t)qrow0 * Dh + quad * 8];
    const bf16x8 bq01 = *(const bf16x8*)&Q[(size_t)qrow0 * Dh + 32 + quad * 8];
    const bf16x8 bq10 = *(const bf16x8*)&Q[(size_t)qrow1 * Dh + quad * 8];
    const bf16x8 bq11 = *(const bf16x8*)&Q[(size_t)qrow1 * Dh + 32 + quad * 8];

    f32x4 O0[4], O1[4];   // O^T per frag: col q = l15, row d = nb*16+quad*4+r
#pragma unroll
    for (int nb = 0; nb < 4; ++nb) {
      O0[nb] = (f32x4){0.f, 0.f, 0.f, 0.f};
      O1[nb] = (f32x4){0.f, 0.f, 0.f, 0.f};
    }
    float l0 = 0.f, l1 = 0.f;   // per-lane partial softmax sums per frag

    BARRIER();   // previous phase's last readers done before re-staging
    STAGE(0, 0);
    STAGE(1, 1);   // 8 DMA outstanding (jmax >= 1: both tiles always valid)

    int cur = 0;
    for (int j = 0; j <= jmax; ++j) {
      if (j < jmax) vmwait<4>();   // own ledger: stage j landed; j+1 in flight
      else          vmwait<0>();
      BARRIER();   // buf[cur] globally complete; reads of buf[(j-1)%3] done

      if (j + 2 <= jmax) {
        int nb2 = cur + 2; if (nb2 >= 3) nb2 -= 3;   // == (j-1)%3: freed above
        STAGE(j + 2, nb2);
      }

      const int kb   = j * 64;
      const int rel0 = Q16_0 - 4 * j;              // frag0 diag sub-tile idx
      const int rel1 = rel0 + 1;
      const int tmax0 = (rel0 >= 3) ? 4 : (rel0 + 1);   // min(4, rel+1)
      const int tmax1 = (rel1 >= 3) ? 4 : (rel1 + 1);
      const u16* KT = Kl[cur];
      const u16* VL = Vt[cur];

      if (tmax1 > 0) {   // wave-uniform: any work this tile
        const bool do0 = (tmax0 > 0);

        // S^T for both frags, sharing every K read.
        f32x4 S0[4], S1[4];
#pragma unroll
        for (int t = 0; t < 4; ++t) {
          S0[t] = (f32x4){0.f, 0.f, 0.f, 0.f};
          S1[t] = (f32x4){0.f, 0.f, 0.f, 0.f};
        }
        __builtin_amdgcn_s_setprio(1);
#pragma unroll
        for (int t = 0; t < 4; ++t) {
          if (t < tmax1) {
            const bf16x8 ak  = *(const bf16x8*)&KT[(t * 16 + l15) * 64 + ((quad * 8) ^ cswz)];
            const bf16x8 ak2 = *(const bf16x8*)&KT[(t * 16 + l15) * 64 + ((quad * 8 + 32) ^ cswz)];
            if (t < tmax0) {
              S0[t] = __builtin_amdgcn_mfma_f32_16x16x32_bf16(ak,  bq00, S0[t], 0, 0, 0);
              S0[t] = __builtin_amdgcn_mfma_f32_16x16x32_bf16(ak2, bq01, S0[t], 0, 0, 0);
            }
            S1[t] = __builtin_amdgcn_mfma_f32_16x16x32_bf16(ak,  bq10, S1[t], 0, 0, 0);
            S1[t] = __builtin_amdgcn_mfma_f32_16x16x32_bf16(ak2, bq11, S1[t], 0, 0, 0);
          }
        }
        __builtin_amdgcn_s_setprio(0);

        // p = exp2(s); masked -> 0. Pack to bf16 immediately (frees S/p).
        u32x4 puA1, puB1;
        {
          float p[4][4];
          if (rel1 >= 4) {
#pragma unroll
            for (int t = 0; t < 4; ++t)
#pragma unroll
              for (int r = 0; r < 4; ++r) {
                p[t][r] = fast_exp2(S1[t][r]); l1 += p[t][r];
              }
          } else {
#pragma unroll
            for (int t = 0; t < 4; ++t) {
              const int key0 = kb + t * 16 + quad * 4;
#pragma unroll
              for (int r = 0; r < 4; ++r) {
                const float sv =
                    (t < tmax1 && key0 + r <= qrow1) ? S1[t][r] : NEG_BIG;
                p[t][r] = fast_exp2(sv); l1 += p[t][r];
              }
            }
          }
          puA1[0] = pack2bf_trunc(p[0][0], p[0][1]);
          puA1[1] = pack2bf_trunc(p[0][2], p[0][3]);
          puA1[2] = pack2bf_trunc(p[1][0], p[1][1]);
          puA1[3] = pack2bf_trunc(p[1][2], p[1][3]);
          puB1[0] = pack2bf_trunc(p[2][0], p[2][1]);
          puB1[1] = pack2bf_trunc(p[2][2], p[2][3]);
          puB1[2] = pack2bf_trunc(p[3][0], p[3][1]);
          puB1[3] = pack2bf_trunc(p[3][2], p[3][3]);
        }
        u32x4 puA0 = (u32x4){0u, 0u, 0u, 0u}, puB0 = (u32x4){0u, 0u, 0u, 0u};
        if (do0) {
          float p[4][4];
          if (rel0 >= 4) {
#pragma unroll
            for (int t = 0; t < 4; ++t)
#pragma unroll
              for (int r = 0; r < 4; ++r) {
                p[t][r] = fast_exp2(S0[t][r]); l0 += p[t][r];
              }
          } else {
#pragma unroll
            for (int t = 0; t < 4; ++t) {
              const int key0 = kb + t * 16 + quad * 4;
#pragma unroll
              for (int r = 0; r < 4; ++r) {
                const float sv =
                    (t < tmax0 && key0 + r <= qrow0) ? S0[t][r] : NEG_BIG;
                p[t][r] = fast_exp2(sv); l0 += p[t][r];
              }
            }
          }
          puA0[0] = pack2bf_trunc(p[0][0], p[0][1]);
          puA0[1] = pack2bf_trunc(p[0][2], p[0][3]);
          puA0[2] = pack2bf_trunc(p[1][0], p[1][1]);
          puA0[3] = pack2bf_trunc(p[1][2], p[1][3]);
          puB0[0] = pack2bf_trunc(p[2][0], p[2][1]);
          puB0[1] = pack2bf_trunc(p[2][2], p[2][3]);
          puB0[2] = pack2bf_trunc(p[3][0], p[3][1]);
          puB0[3] = pack2bf_trunc(p[3][2], p[3][3]);
        }

        // PV chunk 0 (keys 0..31 = tiles 0,1): V reads shared by both frags.
        {
          const bf16x8 pb1 = __builtin_bit_cast(bf16x8, puA1);
          const bf16x8 pb0 = __builtin_bit_cast(bf16x8, puA0);
          __builtin_amdgcn_s_setprio(1);
#pragma unroll
          for (int nb = 0; nb < 4; ++nb) {
            const uint2 a0 = *(const uint2*)&VL[(nb * 16 + l15) * 64 + ((quad * 4) ^ cswz)];
            const uint2 a1 = *(const uint2*)&VL[(nb * 16 + l15) * 64 + ((quad * 4 + 16) ^ cswz)];
            const u32x4 au = {a0.x, a0.y, a1.x, a1.y};
            const bf16x8 av = __builtin_bit_cast(bf16x8, au);
            O1[nb] = __builtin_amdgcn_mfma_f32_16x16x32_bf16(av, pb1, O1[nb], 0, 0, 0);
            if (do0)
              O0[nb] = __builtin_amdgcn_mfma_f32_16x16x32_bf16(av, pb0, O0[nb], 0, 0, 0);
          }
          __builtin_amdgcn_s_setprio(0);
        }
        if (tmax1 > 2) {   // PV chunk 1 (keys 32..63 = tiles 2,3)
          const bf16x8 pb1 = __builtin_bit_cast(bf16x8, puB1);
          const bf16x8 pb0 = __builtin_bit_cast(bf16x8, puB0);
          const bool c20 = (tmax0 > 2);
          __builtin_amdgcn_s_setprio(1);
#pragma unroll
          for (int nb = 0; nb < 4; ++nb) {
            const uint2 a0 = *(const uint2*)&VL[(nb * 16 + l15) * 64 + ((quad * 4 + 32) ^ cswz)];
            const uint2 a1 = *(const uint2*)&VL[(nb * 16 + l15) * 64 + ((quad * 4 + 48) ^ cswz)];
            const u32x4 au = {a0.x, a0.y, a1.x, a1.y};
            const bf16x8 av = __builtin_bit_cast(bf16x8, au);
            O1[nb] = __builtin_amdgcn_mfma_f32_16x16x32_bf16(av, pb1, O1[nb], 0, 0, 0);
            if (c20)
              O0[nb] = __builtin_amdgcn_mfma_f32_16x16x32_bf16(av, pb0, O0[nb], 0, 0, 0);
          }
          __builtin_amdgcn_s_setprio(0);
        }
      }
      cur = (cur == 2) ? 0 : cur + 1;   // single barrier per tile
    }

    // Cross-lane l reductions (sum over quads per q-row), then write out.
    float lt0 = l0 + __shfl_xor(l0, 16, 64);
    lt0 += __shfl_xor(lt0, 32, 64);
    const float inv0 = 1.0f / lt0;
    float lt1 = l1 + __shfl_xor(l1, 16, 64);
    lt1 += __shfl_xor(lt1, 32, 64);
    const float inv1 = 1.0f / lt1;
#pragma unroll
    for (int nb = 0; nb < 4; ++nb) {
      uint2 st;
      st.x = pack2bf(O0[nb][0] * inv0, O0[nb][1] * inv0);
      st.y = pack2bf(O0[nb][2] * inv0, O0[nb][3] * inv0);
      *(uint2*)&outp[(size_t)(b * Tsz + qrow0) * Csz + h * Dh + nb * 16 + quad * 4] = st;
      st.x = pack2bf(O1[nb][0] * inv1, O1[nb][1] * inv1);
      st.y = pack2bf(O1[nb][2] * inv1, O1[nb][3] * inv1);
      *(uint2*)&outp[(size_t)(b * Tsz + qrow1) * Csz + h * Dh + nb * 16 + quad * 4] = st;
    }
  }
#undef STAGE
}

// ---------------------------------------------------------------------------
extern "C" void kernel_launch(void* const* d_in, const int* in_sizes, int n_in,
                              void* d_out, int out_size, void* d_ws, size_t ws_size,
                              hipStream_t stream) {
  const float* x      = (const float*)d_in[0];   // [B,T,C] fp32
  const float* W_attn = (const float*)d_in[1];   // [C,3C]  fp32
  const float* b_attn = (const float*)d_in[2];   // [3C]    fp32
  const float* W_proj = (const float*)d_in[3];   // [C,C]   fp32
  const float* b_proj = (const float*)d_in[4];   // [C]     fp32
  float* out = (float*)d_out;                    // [B,T,C] fp32

  u16* ws   = (u16*)d_ws;
  u16* xbf  = ws;                                // [B,T,C] bf16
  u16* qbuf = xbf  + (size_t)Mrows * Csz;        // [bh][t][d] (pre-scaled)
  u16* kbuf = qbuf + (size_t)Mrows * Csz;        // [bh][t][d]
  u16* vbuf = kbuf + (size_t)Mrows * Csz;        // [bh][d][t]  (transposed!)
  u16* aout = vbuf + (size_t)Mrows * Csz;        // [B,T,C] bf16
  u16* WTa  = aout + (size_t)Mrows * Csz;        // [3C][C] bf16
  u16* WTp  = WTa  + (size_t)Csz * 3 * Csz;      // [C][C]  bf16

  prep<<<CVT_BLKS + TRA_BLKS + TRP_BLKS, 256, 0, stream>>>(
      x, xbf, W_attn, WTa, W_proj, WTp);
  // 128x128 tile, 256 thr: grid 24x64 = 1536 blocks, 3 blocks/CU.
  gemm_bt<0><<<dim3(3 * Csz / 128, Mrows / 128), dim3(256), 0, stream>>>(
      xbf, WTa, b_attn, qbuf, kbuf, vbuf, nullptr, 3 * Csz);
  // QBLK=128 attn: grid (bh=64, y=8) = 512 blocks, all-resident at 3/CU.
  attn_fused<<<dim3(Bsz * Hn, Tsz / 256), 256, 0, stream>>>(
      qbuf, kbuf, vbuf, aout);
  // 128x128 tile, 256 thr: grid 8x64 = 512 blocks.
  gemm_bt<1><<<dim3(Csz / 128, Mrows / 128), dim3(256), 0, stream>>>(
      aout, WTp, b_proj, nullptr, nullptr, nullptr, out, Csz);
}

// Round 12
// 242.659 us; speedup vs baseline: 1.0952x; 1.0522x over previous
//
#include <hip/hip_runtime.h>
#include <cstdint>
#include <cstddef>

// Problem constants (B=4, T=2048, C=1024, H=16, D=64). I/O dtype: fp32.
#define Bsz   4
#define Tsz   2048
#define Csz   1024
#define Hn    16
#define Dh    64
#define Mrows 8192        // B*T
#define KD    1024        // K dim of both GEMMs (= C)

#define NEG_BIG (-1.0e30f)   // finite mask sentinel: exp2(NEG_BIG) flushes to 0
#define SCL2  0.18033688011112042f  // (1/sqrt(64)) * log2(e): folded into Q at
// the QKV epilogue. p = exp2(s) directly; uniform 2^bias cancels in sum(pv)/sum(p).

typedef unsigned short u16;
typedef __bf16  bf16x8 __attribute__((ext_vector_type(8)));
typedef __bf16  bf16x2 __attribute__((ext_vector_type(2)));
typedef float   f32x4  __attribute__((ext_vector_type(4)));
typedef unsigned int u32x4 __attribute__((ext_vector_type(4)));

// Raw barrier + compiler memory fences on both sides (no implicit vmcnt(0)
// drain -- that drain is the structural stall of __syncthreads pipelines).
#define BARRIER() do { asm volatile("" ::: "memory");                          \
                       __builtin_amdgcn_s_barrier();                           \
                       asm volatile("" ::: "memory"); } while (0)

// Literal-immediate vmcnt dispatcher (asm needs compile-time immediates).
template<int N> __device__ __forceinline__ void vmwait() {
  if constexpr (N >= 8)      asm volatile("s_waitcnt vmcnt(8)"  ::: "memory");
  else if constexpr (N == 4) asm volatile("s_waitcnt vmcnt(4)"  ::: "memory");
  else                       asm volatile("s_waitcnt vmcnt(0)"  ::: "memory");
}

__device__ __forceinline__ u16 f2bf(float f) {
  union { float f; unsigned int i; } v; v.f = f;
  unsigned int u = v.i;
  return (u16)((u + 0x7fffu + ((u >> 16) & 1u)) >> 16);   // RNE
}
// Pack two f32 -> two bf16 in one uint (low = a, high = b), RNE.
__device__ __forceinline__ unsigned int pack2bf(float a, float b) {
#if __has_builtin(__builtin_amdgcn_cvt_pk_bf16_f32)
  union { bf16x2 h; unsigned int u; } cv;
  cv.h = __builtin_amdgcn_cvt_pk_bf16_f32(a, b);
  return cv.u;
#else
  return (unsigned int)f2bf(a) | ((unsigned int)f2bf(b) << 16);
#endif
}
// Pack two f32 -> two bf16 by TRUNCATION via one v_perm_b32 (positive P only).
__device__ __forceinline__ unsigned int pack2bf_trunc(float lo, float hi) {
  return __builtin_amdgcn_perm(__builtin_bit_cast(unsigned int, hi),
                               __builtin_bit_cast(unsigned int, lo),
                               0x07060302u);
}
__device__ __forceinline__ float fast_exp2(float x) {
#if __has_builtin(__builtin_amdgcn_exp2f)
  return __builtin_amdgcn_exp2f(x);
#else
  return exp2f(x);
#endif
}

// ---------------------------------------------------------------------------
// Fused preprocessing (ONE launch): region 0 converts x to bf16; regions 1/2
// transpose+convert W_attn / W_proj.
// ---------------------------------------------------------------------------
#define CVT_BLKS  (Mrows * Csz / 4 / 256)   // 8192
#define TRA_BLKS  (48 * 16)                 // W_attn: [1024][3072] -> [3072][1024]
#define TRP_BLKS  (16 * 16)                 // W_proj: [1024][1024] -> [1024][1024]

__global__ __launch_bounds__(256)
void prep(const float* __restrict__ x, u16* __restrict__ xbf,
          const float* __restrict__ Wa, u16* __restrict__ WTa,
          const float* __restrict__ Wp, u16* __restrict__ WTp) {
  __shared__ u16 tile[64][65];
  int bid = blockIdx.x;
  const int tid = threadIdx.x;
  if (bid < CVT_BLKS) {
    const int i = bid * 256 + tid;
    const float4 v = ((const float4*)x)[i];
    uint2 o;
    o.x = pack2bf(v.x, v.y);
    o.y = pack2bf(v.z, v.w);
    ((uint2*)xbf)[i] = o;
    return;
  }
  bid -= CVT_BLKS;
  const float* in; u16* out; int cols, bx, by;
  if (bid < TRA_BLKS) {
    in = Wa; out = WTa; cols = 3 * Csz; bx = bid % 48; by = bid / 48;
  } else {
    bid -= TRA_BLKS;
    in = Wp; out = WTp; cols = Csz; bx = bid & 15; by = bid >> 4;
  }
  const int tc = bx * 64, tr = by * 64;
  const int xx = tid & 63, y0 = tid >> 6;
#pragma unroll
  for (int yy = 0; yy < 64; yy += 4) {
    int r = yy + y0;
    tile[r][xx] = f2bf(in[(size_t)(tr + r) * cols + tc + xx]);
  }
  __syncthreads();
#pragma unroll
  for (int yy = 0; yy < 64; yy += 4) {
    int r = yy + y0;
    out[(size_t)(tc + r) * Csz + tr + xx] = tile[xx][r];
  }
}

// ---------------------------------------------------------------------------
// GEMM C[M,N] = A[M,K] * BT[N,K]^T + bias[N], bf16 in, fp32 acc.
// V8 (round-8, best measured: gemm<0> 74.1 us): 128x128, BK=32, 4 waves 2x2,
// 3-STAGE LDS rotation with ONE barrier per K-step, counted vmcnt(4),
// 4-slot XOR swizzle (pre-swizzled DMA source, 0 conflicts), quadrant-rotated
// reads, setprio, bijective XCD swizzle. 48 KiB LDS -> 3 blocks/CU
// (grid 1536 = 2 x 768 resident: exactly 2 full rounds, no partial tail).
// MODE 0: QKV epilogue -> q/k scatter [bh][t][d]; Q PRE-SCALED by SCL2;
//         V scatter TRANSPOSED [bh][d][t] (packed 8B stores).
// MODE 1: plain epilogue -> fp32 fout[row*N + col].
// ---------------------------------------------------------------------------
template<int MODE>
__global__ __launch_bounds__(256, 3)
void gemm_bt(const u16* __restrict__ A, const u16* __restrict__ BT,
             const float* __restrict__ bias, u16* __restrict__ o0,
             u16* __restrict__ o1, u16* __restrict__ o2,
             float* __restrict__ fout, int N) {
  __shared__ u16 lsA[3][128 * 32];   // [stage][row][32], slot-swizzled content
  __shared__ u16 lsB[3][128 * 32];
  const int tid  = threadIdx.x;
  const int lane = tid & 63;
  const int wid  = tid >> 6;               // 0..3
  const int wm   = wid & 1, wn = wid >> 1; // wave tile 64x64
  const int quad = lane >> 4, l15 = lane & 15;
  const int rswz = (l15 >> 1) & 3;         // read-side XOR (16B-slot units)

  // Bijective XCD-aware swizzle (grid sizes 1536 / 512, both % 8 == 0).
  int bx, by;
  {
    const int nwg  = gridDim.x * gridDim.y;
    const int orig = (int)blockIdx.y * gridDim.x + (int)blockIdx.x;
    const int cpx  = nwg >> 3;
    const int swz  = (orig & 7) * cpx + (orig >> 3);
    bx = swz % gridDim.x; by = swz / gridDim.x;
  }
  const int m0 = by * 128, n0 = bx * 128;

  f32x4 acc[4][4];
#pragma unroll
  for (int i = 0; i < 4; ++i)
#pragma unroll
    for (int j = 0; j < 4; ++j) acc[i][j] = (f32x4){0.f, 0.f, 0.f, 0.f};

  // Staging: per K-step, wave w DMAs A rows [w*32,w*32+32) and B rows same:
  // 2 instrs each (1 instr = 64 lanes x 16B = 16 rows of 64B). Lane l covers
  // row +(l>>2), slot l&3, with PRE-SWIZZLED source chunk (l&3)^((l>>3)&3)
  // so that LDS[r][s] = G[r][s ^ ((r>>1)&3)] with a LINEAR DMA dest.
  const int srow   = lane >> 2;
  const int schunk = (lane & 3) ^ ((lane >> 3) & 3);
  const u16* gA = A  + (size_t)(m0 + wid * 32 + srow) * KD + schunk * 8;
  const u16* gB = BT + (size_t)(n0 + wid * 32 + srow) * KD + schunk * 8;

  auto gstage = [&](int t, int bb) {
#if __has_builtin(__builtin_amdgcn_global_load_lds)
#pragma unroll
    for (int i = 0; i < 2; ++i)
      __builtin_amdgcn_global_load_lds(
          (const __attribute__((address_space(1))) void*)(gA + (size_t)i * 16 * KD + t * 32),
          (__attribute__((address_space(3))) void*)(&lsA[bb][(wid * 32 + i * 16) * 32]),
          16, 0, 0);
#pragma unroll
    for (int i = 0; i < 2; ++i)
      __builtin_amdgcn_global_load_lds(
          (const __attribute__((address_space(1))) void*)(gB + (size_t)i * 16 * KD + t * 32),
          (__attribute__((address_space(3))) void*)(&lsB[bb][(wid * 32 + i * 16) * 32]),
          16, 0, 0);
#else
#pragma unroll
    for (int cc = 0; cc < 2; ++cc) {
      const int c = tid + cc * 256;
      const int rr = c >> 2, off = c & 3;
      const int dc = (off ^ ((rr >> 1) & 3)) << 3;
      *(uint4*)&lsA[bb][rr * 32 + dc] =
          *(const uint4*)&A[(size_t)(m0 + rr) * KD + t * 32 + off * 8];
    }
#pragma unroll
    for (int cc = 0; cc < 2; ++cc) {
      const int c = tid + cc * 256;
      const int rr = c >> 2, off = c & 3;
      const int dc = (off ^ ((rr >> 1) & 3)) << 3;
      *(uint4*)&lsB[bb][rr * 32 + dc] =
          *(const uint4*)&BT[(size_t)(n0 + rr) * KD + t * 32 + off * 8];
    }
#endif
  };

  // Fragment read helpers. Row within tile: base + m*16 + l15; swizzle term
  // depends only on l15 (bases contribute multiples of 8 to row>>1).
#define READ_B(n_) (*(const bf16x8*)                                           \
    &lsB[cur][(wn * 64 + (n_) * 16 + l15) * 32 + ((quad ^ rswz) << 3)])
#define READ_A(m_) (*(const bf16x8*)                                           \
    &lsA[cur][(wm * 64 + (m_) * 16 + l15) * 32 + ((quad ^ rswz) << 3)])
#define MFMA_ROW(m_, src)                                                      \
  __builtin_amdgcn_s_setprio(1);                                               \
  _Pragma("unroll")                                                            \
  for (int n = 0; n < 4; ++n)                                                  \
    acc[m_][n] = __builtin_amdgcn_mfma_f32_16x16x32_bf16(                      \
        src, bfv[n], acc[m_][n], 0, 0, 0);                                     \
  __builtin_amdgcn_s_setprio(0);

  // 3-stage prologue: stages 0 and 1 in flight (8 DMA outstanding).
  gstage(0, 0); gstage(1, 1);
  const int KT = KD / 32;   // 32
  int cur = 0;
  for (int t = 0; t < KT; ++t) {
    if (t < KT - 1) vmwait<4>();   // own ledger: 8 out -> stage t landed,
    else            vmwait<0>();   // stage t+1's 4 stay in flight
    BARRIER();   // buf[cur] globally complete; reads of buf[(t-1)%3] all done

    if (t + 2 < KT) {
      int nb2 = cur + 2; if (nb2 >= 3) nb2 -= 3;   // == (t-1)%3: freed above
      gstage(t + 2, nb2);
    }

    bf16x8 bfv[4];
#pragma unroll
    for (int n = 0; n < 4; ++n) bfv[n] = READ_B(n);
    bf16x8 afA = READ_A(0);
    bf16x8 afB = READ_A(1);
    MFMA_ROW(0, afA);
    afA = READ_A(2);
    MFMA_ROW(1, afB);
    afB = READ_A(3);
    MFMA_ROW(2, afA);
    MFMA_ROW(3, afB);

    cur = (cur == 2) ? 0 : cur + 1;   // single barrier per step: no tail sync
  }
#undef READ_B
#undef READ_A
#undef MFMA_ROW

  // Epilogue. C/D layout: col = lane&15, row = quad*4 + r (verified m89/m91).
#pragma unroll
  for (int i = 0; i < 4; ++i) {
#pragma unroll
    for (int j = 0; j < 4; ++j) {
      const int colb = n0 + wn * 64 + j * 16 + l15;
      const float bv = bias[colb];
      float vals[4];
#pragma unroll
      for (int r = 0; r < 4; ++r) vals[r] = acc[i][j][r] + bv;
      const int row0 = m0 + wm * 64 + i * 16 + quad * 4;
      if (MODE == 0) {
        const int b = row0 >> 11, t0 = row0 & (Tsz - 1);
        const int region = colb >> 10;        // 0:q 1:k 2:v (fragment-uniform)
        const int nc = colb & (Csz - 1);
        const int h = nc >> 6, d = nc & 63;
        if (region == 2) {
          // V transposed: [bh][d][t]; 4 consecutive t -> one 8B store.
          uint2 st;
          st.x = pack2bf(vals[0], vals[1]);
          st.y = pack2bf(vals[2], vals[3]);
          *(uint2*)&o2[((size_t)((b << 4) + h) * Dh + d) * Tsz + t0] = st;
        } else {
          u16* dst = (region == 0) ? o0 : o1;
          const float qs = (region == 0) ? SCL2 : 1.0f;  // fold softmax scale
#pragma unroll
          for (int r = 0; r < 4; ++r)
            dst[(size_t)(((b << 4) + h) * Tsz + t0 + r) * Dh + d] =
                f2bf(vals[r] * qs);
        }
      } else {
#pragma unroll
        for (int r = 0; r < 4; ++r)
          fout[(size_t)(row0 + r) * N + colb] = vals[r];
      }
    }
  }
}

// ---------------------------------------------------------------------------
// Fused causal flash attention, V12: round-5 compute body (best measured,
// VGPR ~68, 32 KiB LDS, grid 1024 all-resident at 4 blocks/CU) with the
// round-8 barrier deletion: ONE barrier per KV-tile, STAGE moved AFTER the
// barrier (2-buffer rotation).
//   iter j: vmwait(0) [outstanding = exactly stage j's 4 DMA, issued one full
//   compute-phase earlier -- identical wait to the old vmwait(4) at 8 out]
//   -> BARRIER [buf j&1 globally complete AND all waves done reading
//   buf (j-1)&1 in iter j-1] -> STAGE(j+1) into buf (j+1)&1 == (j-1)&1
//   [race-free: its readers finished before this barrier] -> compute.
// Deletes 1 barrier per tile (66 -> 35 per block) -- the only lever that
// moved a kernel in 12 rounds (gemm round 8: -6%).
// Phase-start BARRIER protects buf0/1 from the previous phase's readers.
// grid (bh=64, y=16), 256 threads; block handles jq=31-y then jq=y.
// ---------------------------------------------------------------------------
__global__ __launch_bounds__(256)
void attn_fused(const u16* __restrict__ qb, const u16* __restrict__ kbuf,
                const u16* __restrict__ vT, u16* __restrict__ outp) {
  __shared__ u16 Kl[2][64 * 64];   // [buf][key][d],  chunk-swizzled content
  __shared__ u16 Vt[2][64 * 64];   // [buf][d][key],  chunk-swizzled content
  const int tid = threadIdx.x, lane = tid & 63, w = tid >> 6;
  const int quad = lane >> 4, l15 = lane & 15;
  const int cswz = (l15 & 7) << 3;        // read-side XOR swizzle (u16 units)
  const int bh = blockIdx.x;
  const int b = bh >> 4, h = bh & 15;
  const u16* Q   = qb   + (size_t)bh * Tsz * Dh;
  const u16* Kg  = kbuf + (size_t)bh * Tsz * Dh;
  const u16* VTg = vT   + (size_t)bh * Dh * Tsz;

  const int srow   = lane >> 3;
  const int schunk = ((lane & 7) ^ srow) << 3;       // u16 offset in row
  const u16* gK0 = Kg  + (size_t)(w * 16 + srow) * Dh  + schunk;
  const u16* gV0 = VTg + (size_t)(w * 16 + srow) * Tsz + schunk;

#if __has_builtin(__builtin_amdgcn_global_load_lds)
#define STAGE(jj, bb) do {                                                     \
    const size_t kb_ = (size_t)(jj) * 64;                                      \
    _Pragma("unroll")                                                          \
    for (int i_ = 0; i_ < 2; ++i_) {                                           \
      __builtin_amdgcn_global_load_lds(                                        \
        (const __attribute__((address_space(1))) void*)(gK0 + (kb_ + (size_t)i_ * 8) * Dh), \
        (__attribute__((address_space(3))) void*)(&Kl[bb][(w * 16 + i_ * 8) * 64]), 16, 0, 0); \
      __builtin_amdgcn_global_load_lds(                                        \
        (const __attribute__((address_space(1))) void*)(gV0 + (size_t)(i_ * 8) * Tsz + kb_), \
        (__attribute__((address_space(3))) void*)(&Vt[bb][(w * 16 + i_ * 8) * 64]), 16, 0, 0); \
    }                                                                          \
  } while (0)
#else
#define STAGE(jj, bb) do {                                                     \
    const int kb_ = (jj) * 64;                                                 \
    _Pragma("unroll")                                                          \
    for (int cc_ = 0; cc_ < 2; ++cc_) {                                        \
      const int c_ = tid + cc_ * 256;                                          \
      const int rr_ = c_ >> 3, off_ = c_ & 7;                                  \
      const int dc_ = (off_ ^ (rr_ & 7)) << 3;                                 \
      *(uint4*)&Kl[bb][rr_ * 64 + dc_] =                                       \
          *(const uint4*)&Kg[(size_t)(kb_ + rr_) * Dh + off_ * 8];             \
      *(uint4*)&Vt[bb][rr_ * 64 + dc_] =                                       \
          *(const uint4*)&VTg[(size_t)rr_ * Tsz + kb_ + off_ * 8];             \
    }                                                                          \
  } while (0)
#endif

  for (int ph = 0; ph < 2; ++ph) {
    const int jq = ph ? (int)blockIdx.y : 31 - (int)blockIdx.y;

    // Q fragment (B-operand of S^T): lane holds Q[q=l15][d=quad*8+j].
    const int qrow = jq * 64 + w * 16 + l15;   // this lane's q (global row)
    const bf16x8 bq0 = *(const bf16x8*)&Q[(size_t)qrow * Dh + quad * 8];
    const bf16x8 bq1 = *(const bf16x8*)&Q[(size_t)qrow * Dh + 32 + quad * 8];

    f32x4 O[4];    // O^T: col q = l15, row d = nb*16 + quad*4 + r
#pragma unroll
    for (int nb = 0; nb < 4; ++nb) O[nb] = (f32x4){0.f, 0.f, 0.f, 0.f};
    float l_i = 0.f;               // per-lane partial sum (16 keys/lane/tile)

    BARRIER();     // previous phase's last readers done before re-staging
    STAGE(0, 0);   // 4 DMA outstanding

    for (int j = 0; j <= jq; ++j) {
      const int cur = j & 1;
      vmwait<0>();   // own stage-j slice landed (issued one phase earlier)
      BARRIER();     // buf[cur] globally complete; reads of buf[cur^1] done

      if (j < jq) STAGE(j + 1, cur ^ 1);   // into the buffer freed above

      const int kb = j * 64;
      const bool diag = (j == jq);
      const int tmax = diag ? (w + 1) : 4;   // 16-key sub-tiles with any work
      const u16* KT = Kl[cur];
      const u16* VL = Vt[cur];

      // S^T: A = K fragment (m=key=16t+l15, k=d=quad*8+jj), B = Q fragment.
      f32x4 S[4];
#pragma unroll
      for (int t = 0; t < 4; ++t) S[t] = (f32x4){0.f, 0.f, 0.f, 0.f};
      __builtin_amdgcn_s_setprio(1);
#pragma unroll
      for (int t = 0; t < 4; ++t) {
        if (t < tmax) {
          bf16x8 ak = *(const bf16x8*)&KT[(t * 16 + l15) * 64 + ((quad * 8) ^ cswz)];
          S[t] = __builtin_amdgcn_mfma_f32_16x16x32_bf16(ak, bq0, S[t], 0, 0, 0);
          ak = *(const bf16x8*)&KT[(t * 16 + l15) * 64 + ((quad * 8 + 32) ^ cswz)];
          S[t] = __builtin_amdgcn_mfma_f32_16x16x32_bf16(ak, bq1, S[t], 0, 0, 0);
        }
      }
      __builtin_amdgcn_s_setprio(0);

      // p = exp2(s) directly (scale pre-folded into Q); masked -> 0.
      float p[4][4];
      if (diag) {
#pragma unroll
        for (int t = 0; t < 4; ++t) {
          const int key0 = kb + t * 16 + quad * 4;
#pragma unroll
          for (int r = 0; r < 4; ++r) {
            const float sv =
                (t < tmax && key0 + r <= qrow) ? S[t][r] : NEG_BIG;
            p[t][r] = fast_exp2(sv);
            l_i += p[t][r];
          }
        }
      } else {
#pragma unroll
        for (int t = 0; t < 4; ++t)
#pragma unroll
          for (int r = 0; r < 4; ++r) {
            p[t][r] = fast_exp2(S[t][r]);
            l_i += p[t][r];
          }
      }

      // PV chunk 0 (keys 0..31 = tiles 0,1): B-frag key pi(quad*8+jj).
      u32x4 pu;
      pu[0] = pack2bf_trunc(p[0][0], p[0][1]);
      pu[1] = pack2bf_trunc(p[0][2], p[0][3]);
      pu[2] = pack2bf_trunc(p[1][0], p[1][1]);
      pu[3] = pack2bf_trunc(p[1][2], p[1][3]);
      bf16x8 pb = __builtin_bit_cast(bf16x8, pu);
      __builtin_amdgcn_s_setprio(1);
#pragma unroll
      for (int nb = 0; nb < 4; ++nb) {
        const uint2 a0 = *(const uint2*)&VL[(nb * 16 + l15) * 64 + ((quad * 4) ^ cswz)];
        const uint2 a1 = *(const uint2*)&VL[(nb * 16 + l15) * 64 + ((quad * 4 + 16) ^ cswz)];
        const u32x4 au = {a0.x, a0.y, a1.x, a1.y};
        O[nb] = __builtin_amdgcn_mfma_f32_16x16x32_bf16(
            __builtin_bit_cast(bf16x8, au), pb, O[nb], 0, 0, 0);
      }
      __builtin_amdgcn_s_setprio(0);
      if (tmax > 2) {   // PV chunk 1 (keys 32..63 = tiles 2,3)
        pu[0] = pack2bf_trunc(p[2][0], p[2][1]);
        pu[1] = pack2bf_trunc(p[2][2], p[2][3]);
        pu[2] = pack2bf_trunc(p[3][0], p[3][1]);
        pu[3] = pack2bf_trunc(p[3][2], p[3][3]);
        pb = __builtin_bit_cast(bf16x8, pu);
        __builtin_amdgcn_s_setprio(1);
#pragma unroll
        for (int nb = 0; nb < 4; ++nb) {
          const uint2 a0 = *(const uint2*)&VL[(nb * 16 + l15) * 64 + ((quad * 4 + 32) ^ cswz)];
          const uint2 a1 = *(const uint2*)&VL[(nb * 16 + l15) * 64 + ((quad * 4 + 48) ^ cswz)];
          const u32x4 au = {a0.x, a0.y, a1.x, a1.y};
          O[nb] = __builtin_amdgcn_mfma_f32_16x16x32_bf16(
              __builtin_bit_cast(bf16x8, au), pb, O[nb], 0, 0, 0);
        }
        __builtin_amdgcn_s_setprio(0);
      }
      // single barrier per tile: no trailing sync
    }

    // One cross-lane l reduction for the whole phase, then write out.
    float lt = l_i + __shfl_xor(l_i, 16, 64);
    lt += __shfl_xor(lt, 32, 64);
    const float inv = 1.0f / lt;
#pragma unroll
    for (int nb = 0; nb < 4; ++nb) {
      uint2 st;
      st.x = pack2bf(O[nb][0] * inv, O[nb][1] * inv);
      st.y = pack2bf(O[nb][2] * inv, O[nb][3] * inv);
      *(uint2*)&outp[(size_t)(b * Tsz + qrow) * Csz + h * Dh + nb * 16 + quad * 4] = st;
    }
  }
#undef STAGE
}

// ---------------------------------------------------------------------------
extern "C" void kernel_launch(void* const* d_in, const int* in_sizes, int n_in,
                              void* d_out, int out_size, void* d_ws, size_t ws_size,
                              hipStream_t stream) {
  const float* x      = (const float*)d_in[0];   // [B,T,C] fp32
  const float* W_attn = (const float*)d_in[1];   // [C,3C]  fp32
  const float* b_attn = (const float*)d_in[2];   // [3C]    fp32
  const float* W_proj = (const float*)d_in[3];   // [C,C]   fp32
  const float* b_proj = (const float*)d_in[4];   // [C]     fp32
  float* out = (float*)d_out;                    // [B,T,C] fp32

  u16* ws   = (u16*)d_ws;
  u16* xbf  = ws;                                // [B,T,C] bf16
  u16* qbuf = xbf  + (size_t)Mrows * Csz;        // [bh][t][d] (pre-scaled)
  u16* kbuf = qbuf + (size_t)Mrows * Csz;        // [bh][t][d]
  u16* vbuf = kbuf + (size_t)Mrows * Csz;        // [bh][d][t]  (transposed!)
  u16* aout = vbuf + (size_t)Mrows * Csz;        // [B,T,C] bf16
  u16* WTa  = aout + (size_t)Mrows * Csz;        // [3C][C] bf16
  u16* WTp  = WTa  + (size_t)Csz * 3 * Csz;      // [C][C]  bf16

  prep<<<CVT_BLKS + TRA_BLKS + TRP_BLKS, 256, 0, stream>>>(
      x, xbf, W_attn, WTa, W_proj, WTp);
  // 128x128 tile, 256 thr: grid 24x64 = 1536 blocks, 3 blocks/CU.
  gemm_bt<0><<<dim3(3 * Csz / 128, Mrows / 128), dim3(256), 0, stream>>>(
      xbf, WTa, b_attn, qbuf, kbuf, vbuf, nullptr, 3 * Csz);
  // Attn: grid (bh=64, y=16) = 1024 blocks, all-resident at 4 blocks/CU.
  attn_fused<<<dim3(Bsz * Hn, Tsz / 128), 256, 0, stream>>>(
      qbuf, kbuf, vbuf, aout);
  // 128x128 tile, 256 thr: grid 8x64 = 512 blocks.
  gemm_bt<1><<<dim3(Csz / 128, Mrows / 128), dim3(256), 0, stream>>>(
      aout, WTp, b_proj, nullptr, nullptr, nullptr, out, Csz);
}